// Round 11
// baseline (103.041 us; speedup 1.0000x reference)
//
#include <hip/hip_runtime.h>

#define B 128
#define S 512
#define T 64

typedef float f32x4 __attribute__((ext_vector_type(4)));
typedef _Float16 h2 __attribute__((ext_vector_type(2)));
typedef _Float16 h8 __attribute__((ext_vector_type(8)));

__device__ __forceinline__ float rdlane(float v, int l) {
    return __int_as_float(__builtin_amdgcn_readlane(__float_as_int(v), l));
}
__device__ __forceinline__ unsigned cvtpk_bf16(float lo, float hi) {
    unsigned r;
    asm("v_cvt_pk_bf16_f32 %0, %1, %2" : "=v"(r) : "v"(lo), "v"(hi));
    return r;
}
// packed f32->f16 (RTZ), two f16 in one dword
__device__ __forceinline__ unsigned cvt_pkrtz_u(float lo, float hi) {
    unsigned r;
    asm("v_cvt_pkrtz_f16_f32 %0, %1, %2" : "=v"(r) : "v"(lo), "v"(hi));
    return r;
}
__device__ __forceinline__ float fast_exp2(float x) {
    float r;
    asm("v_exp_f32 %0, %1" : "=v"(r) : "v"(x));
    return r;
}
// A/B fragment k-index for mfma_f32_16x16x32_{bf16,f16}, SPLIT-HALF mapping
// (validated round 6, absmax=0): e=0..3 -> k=4*gq+e ; e=4..7 -> k=16+4*gq+(e-4)
__device__ __forceinline__ int krow(int kt, int gq, int e) {
    return 32 * kt + ((e >> 2) << 4) + 4 * gq + (e & 3);
}

// ============================================================================
// Phase 1: 4 waves per 256-thread block, each wave owns one (batch, chunk):
// builds Z_g = prod_t (D_t*E^T) in f16 + pow2 int log-scale via chained
// 64x64x64 f16 MFMAs. Diagonal folded into A (per-fragment-uniform rows);
// C held one column of tiles (16 regs); repack C->B lane-local (cvt_pkrtz).
// ROUND 11: 1-wave workgroups capped residency at ~7 waves/CU (occupancy 22%);
// 4-wave blocks + private relay slabs -> 4 blocks/CU = 16 waves/CU.
// ============================================================================
template<int GG>
__global__ __launch_bounds__(256, 4)
void crf_chunk4(const float* __restrict__ features,
                const float* __restrict__ mask,
                const float* __restrict__ transitions,
                unsigned short* __restrict__ Zout,
                int* __restrict__ Kout)
{
    constexpr int CLT = S / GG;
    __shared__ unsigned short relay[4][T * 68];   // private slab per wave

    const int wid  = threadIdx.x >> 6;
    const int lane = threadIdx.x & 63;
    const int idx  = blockIdx.x * 4 + wid;
    const int b  = idx / GG;
    const int g  = idx % GG;
    const int c  = lane & 15;
    const int gq = lane >> 4;

    // ---- static E^T fragments (f16): Ef[rt][kt][e] = exp(W[k][i]),
    //      i = c + 16*rt, k = krow(kt,gq,e); track E max for the d-clamp.
    h8 Ef[4][2];
    float emaxv = 1e-10f;
    #pragma unroll
    for (int rt = 0; rt < 4; ++rt)
      #pragma unroll
      for (int kt = 0; kt < 2; ++kt)
        #pragma unroll
        for (int e = 0; e < 8; ++e) {
            int k = krow(kt, gq, e);
            float x = __expf(transitions[k * T + (c + 16*rt)]);
            emaxv = fmaxf(emaxv, x);
            Ef[rt][kt][e] = (_Float16)x;
        }
    #pragma unroll
    for (int o = 32; o > 0; o >>= 1)
        emaxv = fmaxf(emaxv, __shfl_xor(emaxv, o));
    const float dmax = 60000.0f / emaxv;   // keeps A' inside f16 range

    // ---- Z init = identity, in B-fragment layout: B[k][col] ----
    h8 Bf[2][4];
    #pragma unroll
    for (int kt = 0; kt < 2; ++kt)
      #pragma unroll
      for (int ct = 0; ct < 4; ++ct)
        #pragma unroll
        for (int e = 0; e < 8; ++e)
            Bf[kt][ct][e] = (krow(kt, gq, e) == 16*ct + c) ? (_Float16)1.0f
                                                           : (_Float16)0.0f;

    const float* fb   = features + (size_t)b * S * T;
    const float* colp = fb + c;            // this lane's A-row column base
    const int t0 = g * CLT + 1;
    const int t1 = (g == GG - 1) ? S : (t0 + CLT);   // exclusive

    int kcur = 0, ktot = 0;

    // emission prefetch: em[t, c+16*rt] (A-row distribution), depth 1
    float emN[4];
    #pragma unroll
    for (int rt = 0; rt < 4; ++rt) emN[rt] = colp[t0 * T + 16*rt];
    float mA = mask[(size_t)b * S + t0];

    for (int t = t0; t < t1; ++t) {
        float emc[4];
        #pragma unroll
        for (int rt = 0; rt < 4; ++rt) emc[rt] = emN[rt];
        float m = mA;
        if (t + 1 < t1) {
            #pragma unroll
            for (int rt = 0; rt < 4; ++rt)
                emN[rt] = colp[(t + 1) * T + 16*rt];
            mA = mask[(size_t)b * S + t + 1];
        }
        if (m != 0.0f) {
            // d_rt = exp(em)*2^-kcur = exp2(em*log2e - kcur), clamped; fold
            // into A row-scale (row i = c + 16*rt is per-fragment-uniform)
            const float kcf = (float)kcur;
            h8 Ap[4][2];
            #pragma unroll
            for (int rt = 0; rt < 4; ++rt) {
                float d = fast_exp2(fmaf(emc[rt], 1.44269504f, -kcf));
                d = fminf(d, dmax);
                unsigned w = cvt_pkrtz_u(d, d);
                uint4 qs; qs.x = w; qs.y = w; qs.z = w; qs.w = w;
                h8 ds = __builtin_bit_cast(h8, qs);
                Ap[rt][0] = Ef[rt][0] * ds;    // v_pk_mul_f16
                Ap[rt][1] = Ef[rt][1] * ds;
            }

            // per output-column ct: 8 MFMAs -> C column (16 regs) ->
            // max-update -> lane-local repack into Bf[*][ct]
            float mx = 1e-30f;
            #pragma unroll
            for (int ct = 0; ct < 4; ++ct) {
                f32x4 Ct[4];
                #pragma unroll
                for (int tr = 0; tr < 4; ++tr) {
                    f32x4 z = {0.f, 0.f, 0.f, 0.f};
                    z = __builtin_amdgcn_mfma_f32_16x16x32_f16(Ap[tr][0], Bf[0][ct], z, 0, 0, 0);
                    z = __builtin_amdgcn_mfma_f32_16x16x32_f16(Ap[tr][1], Bf[1][ct], z, 0, 0, 0);
                    Ct[tr] = z;
                }
                #pragma unroll
                for (int tr = 0; tr < 4; ++tr)
                    mx = fmaxf(mx, fmaxf(fmaxf(Ct[tr][0], Ct[tr][1]),
                                         fmaxf(Ct[tr][2], Ct[tr][3])));
                uint4 q0, q1;
                q0.x = cvt_pkrtz_u(Ct[0][0], Ct[0][1]);
                q0.y = cvt_pkrtz_u(Ct[0][2], Ct[0][3]);
                q0.z = cvt_pkrtz_u(Ct[1][0], Ct[1][1]);
                q0.w = cvt_pkrtz_u(Ct[1][2], Ct[1][3]);
                q1.x = cvt_pkrtz_u(Ct[2][0], Ct[2][1]);
                q1.y = cvt_pkrtz_u(Ct[2][2], Ct[2][3]);
                q1.z = cvt_pkrtz_u(Ct[3][0], Ct[3][1]);
                q1.w = cvt_pkrtz_u(Ct[3][2], Ct[3][3]);
                Bf[0][ct] = __builtin_bit_cast(h8, q0);
                Bf[1][ct] = __builtin_bit_cast(h8, q1);
            }

            // lagged rescale bookkeeping (applied next step via kcur)
            #pragma unroll
            for (int o = 32; o > 0; o >>= 1)
                mx = fmaxf(mx, __shfl_xor(mx, o));
            ktot += kcur;
            kcur = (((__float_as_int(mx) >> 23) & 0xFF) - 127) + 8;
            kcur = kcur < -60 ? -60 : (kcur > 60 ? 60 : kcur);
        }
    }

    // ---- ONE-TIME: f16 frags -> bf16 dwords, relayout via private LDS ----
    unsigned short* rl = relay[wid];
    #pragma unroll
    for (int kt = 0; kt < 2; ++kt)
      #pragma unroll
      for (int ct = 0; ct < 4; ++ct) {
          int col = 16*ct + c;
          unsigned dw[4];
          #pragma unroll
          for (int p = 0; p < 4; ++p)
              dw[p] = cvtpk_bf16((float)Bf[kt][ct][2*p], (float)Bf[kt][ct][2*p+1]);
          uint2 wa; wa.x = dw[0]; wa.y = dw[1];   // rows 32kt+4gq+0..3
          uint2 wb; wb.x = dw[2]; wb.y = dw[3];   // rows 32kt+16+4gq+0..3
          *(uint2*)&rl[col * 68 + 32*kt      + 4*gq] = wa;
          *(uint2*)&rl[col * 68 + 32*kt + 16 + 4*gq] = wb;
      }
    asm volatile("s_waitcnt lgkmcnt(0)" ::: "memory");

    // each lane reads its row (row = lane) across cols, stores row-major
    unsigned short* zo = Zout + ((size_t)(b * GG + g)) * 64 * 64;
    #pragma unroll
    for (int q8 = 0; q8 < 8; ++q8) {
        unsigned dw[4];
        #pragma unroll
        for (int d = 0; d < 4; ++d) {
            unsigned lo = rl[(8*q8 + 2*d    ) * 68 + lane];
            unsigned hi = rl[(8*q8 + 2*d + 1) * 68 + lane];
            dw[d] = lo | (hi << 16);
        }
        uint4 w; w.x = dw[0]; w.y = dw[1]; w.z = dw[2]; w.w = dw[3];
        *(uint4*)(zo + (size_t)lane * 64 + 8*q8) = w;
    }
    if (lane == 0) Kout[b * GG + g] = ktot;
}

// ============================================================================
// Phase 2: one wave per batch. v = exp(alpha - max), apply the GG chunk
// matrices sequentially (v <- Z_g v), renormalize by wave-max; plus gold.
// 4 independent accumulators cut the serial fma chain 64 -> 16 deep.
// ============================================================================
template<int GG>
__global__ __launch_bounds__(64, 1)
void crf_apply(const float* __restrict__ features,
               const int*   __restrict__ labels,
               const float* __restrict__ mask,
               const float* __restrict__ transitions,
               const unsigned short* __restrict__ Zmat,
               const int*   __restrict__ Kscale,
               float*       __restrict__ res)
{
    __shared__ float trans_lds[T * T];
    __shared__ float bcast[2][T];
    const int lane = threadIdx.x;
    const int b = blockIdx.x;

    for (int i = 0; i < T; ++i)
        trans_lds[i * T + lane] = transitions[i * T + lane];
    __syncthreads();

    const float* fb = features + (size_t)b * S * T;
    const int*   lb = labels + (size_t)b * S;
    const float* mb = mask + (size_t)b * S;

    // ---- gold score (lane i handles t = 64*ch + i) ----
    float gold = 0.f;
    #pragma unroll
    for (int ch = 0; ch < S / T; ++ch) {
        int tt = ch * T + lane;
        int tm1 = tt > 0 ? tt - 1 : 0;
        int la = lb[tt], lp = lb[tm1];
        float mt = mb[tt], mp = mb[tm1];
        float em_g = fb[(size_t)tt * T + la];
        float tr_g = trans_lds[lp * T + la];
        gold += em_g * mt + ((tt > 0) ? tr_g * (mp * mt) : 0.f);
    }

    // ---- v init from alpha_0 = em_0, normalized by wave max ----
    float a0 = fb[lane];
    float A0 = a0;
    #pragma unroll
    for (int o = 32; o > 0; o >>= 1) A0 = fmaxf(A0, __shfl_xor(A0, o));
    float v = __expf(a0 - A0);
    float off = A0;

    // double-buffered Z-row loads (lane j holds row j)
    const unsigned short* zb = Zmat + ((size_t)b * GG) * 64 * 64 + (size_t)lane * 64;
    uint4 cur[8], nxt[8];
    #pragma unroll
    for (int i = 0; i < 8; ++i) cur[i] = ((const uint4*)zb)[i];

    for (int g = 0; g < GG; ++g) {
        if (g + 1 < GG) {
            const uint4* zn = (const uint4*)(zb + (size_t)(g + 1) * 64 * 64);
            #pragma unroll
            for (int i = 0; i < 8; ++i) nxt[i] = zn[i];
        }
        const int buf = g & 1;
        bcast[buf][lane] = v;
        asm volatile("s_waitcnt lgkmcnt(0)" ::: "memory");
        f32x4 vb[16];
        #pragma unroll
        for (int q = 0; q < 16; ++q) vb[q] = ((const f32x4*)bcast[buf])[q];

        float ac0 = 0.f, ac1 = 0.f, ac2 = 0.f, ac3 = 0.f;
        #pragma unroll
        for (int i = 0; i < 8; ++i) {
            unsigned zz[4] = {cur[i].x, cur[i].y, cur[i].z, cur[i].w};
            #pragma unroll
            for (int d = 0; d < 4; ++d) {
                int k = i * 8 + d * 2;
                float f0 = __int_as_float(zz[d] << 16);
                float f1 = __int_as_float(zz[d] & 0xFFFF0000u);
                if (d == 0) { ac0 = fmaf(f0, vb[k >> 2][k & 3], ac0);
                              ac1 = fmaf(f1, vb[(k+1) >> 2][(k+1) & 3], ac1); }
                else if (d == 1) { ac2 = fmaf(f0, vb[k >> 2][k & 3], ac2);
                                   ac3 = fmaf(f1, vb[(k+1) >> 2][(k+1) & 3], ac3); }
                else if (d == 2) { ac0 = fmaf(f0, vb[k >> 2][k & 3], ac0);
                                   ac1 = fmaf(f1, vb[(k+1) >> 2][(k+1) & 3], ac1); }
                else { ac2 = fmaf(f0, vb[k >> 2][k & 3], ac2);
                       ac3 = fmaf(f1, vb[(k+1) >> 2][(k+1) & 3], ac3); }
            }
        }
        float acc = (ac0 + ac1) + (ac2 + ac3);
        acc = fminf(fmaxf(acc, 0.f), 1e30f);
        float r = acc;
        #pragma unroll
        for (int o = 32; o > 0; o >>= 1) r = fmaxf(r, __shfl_xor(r, o));
        r = fmaxf(r, 1e-30f);
        v = acc / r;
        off += __logf(r) + (float)Kscale[b * GG + g] * 0.69314718056f;
        #pragma unroll
        for (int i = 0; i < 8; ++i) cur[i] = nxt[i];
    }

    float sum = v;
    #pragma unroll
    for (int o = 32; o > 0; o >>= 1) sum += __shfl_xor(sum, o);
    float logZ = __logf(fmaxf(sum, 1e-30f)) + off;

    #pragma unroll
    for (int o = 32; o > 0; o >>= 1) gold += __shfl_xor(gold, o);

    if (lane == 0) res[b] = logZ - gold;
}

// ============================================================================
// Fallback: validated round-3 sequential kernel (used if ws too small)
// ============================================================================
__global__ __launch_bounds__(64, 1)
void crf_fwd_seq(const float* __restrict__ features,
                 const int*   __restrict__ labels,
                 const float* __restrict__ mask,
                 const float* __restrict__ transitions,
                 float*       __restrict__ ws)
{
    __shared__ float trans_lds[T * T];
    __shared__ __align__(16) _Float16 ea_lds[2][T];

    const int lane = threadIdx.x;
    const int b    = blockIdx.x;

    for (int i = 0; i < T; ++i)
        trans_lds[i * T + lane] = transitions[i * T + lane];
    __syncthreads();

    h2 etr[T / 2];
    #pragma unroll
    for (int k = 0; k < T / 2; ++k) {
        etr[k].x = (_Float16)__expf(trans_lds[(2 * k + 0) * T + lane]);
        etr[k].y = (_Float16)__expf(trans_lds[(2 * k + 1) * T + lane]);
    }

    const float* fb = features + (size_t)b * S * T;
    const float* mb = mask + (size_t)b * S;
    const int*   lb = labels + (size_t)b * S;

    float alpha = fb[lane];
    float gold_part = 0.f;
    float M = 0.f;

    float em_n1 = fb[1 * T + lane];
    float em_n2 = fb[2 * T + lane];
    float em_n3 = fb[3 * T + lane];

    int   lab_c = lb[lane];
    int   lab_p = lb[lane > 0 ? lane - 1 : 0];
    float m_c   = mb[lane];
    float m_p   = mb[lane > 0 ? lane - 1 : 0];

    for (int ch = 0; ch < S / T; ++ch) {
        const int base = ch * T;
        const int tt   = base + lane;

        const int   glab  = lab_c;
        const int   glabp = lab_p;
        const float gmc   = m_c;
        const float gmp   = m_p;
        const float mreg  = m_c;

        float em_g = fb[(size_t)tt * T + glab];
        float tr_g = trans_lds[glabp * T + glab];

        {
            int tn  = tt + T;  if (tn > S - 1) tn = S - 1;
            int tnp = tn - 1;  if (tnp < 0) tnp = 0;
            lab_c = lb[tn]; lab_p = lb[tnp];
            m_c   = mb[tn]; m_p   = mb[tnp];
        }

        const int i0 = (ch == 0) ? 1 : 0;
        #pragma unroll 4
        for (int i = i0; i < T; ++i) {
            const int t = base + i;
            float em = em_n1;
            em_n1 = em_n2; em_n2 = em_n3;
            int tn = t + 3; if (tn > S - 1) tn = S - 1;
            em_n3 = fb[tn * T + lane];

            float ea = __expf(alpha - M);
            ea_lds[t & 1][lane] = (_Float16)ea;
            asm volatile("s_waitcnt lgkmcnt(0)" ::: "memory");

            const uint4* ep = (const uint4*)&ea_lds[t & 1][0];
            float a0 = 0.f, a1 = 0.f, a2 = 0.f, a3 = 0.f;
            #pragma unroll
            for (int q = 0; q < 8; ++q) {
                uint4 r = ep[q];
                a0 = __builtin_amdgcn_fdot2(__builtin_bit_cast(h2, r.x), etr[4 * q + 0], a0, false);
                a1 = __builtin_amdgcn_fdot2(__builtin_bit_cast(h2, r.y), etr[4 * q + 1], a1, false);
                a2 = __builtin_amdgcn_fdot2(__builtin_bit_cast(h2, r.z), etr[4 * q + 2], a2, false);
                a3 = __builtin_amdgcn_fdot2(__builtin_bit_cast(h2, r.w), etr[4 * q + 3], a3, false);
            }
            float s = (a0 + a1) + (a2 + a3);

            float m_t = rdlane(mreg, i);
            float s1  = rdlane(s, 1);
            float em1 = rdlane(em, 1);
            float Mn  = M + __logf(s1) + em1;

            float val = M + __logf(s) + em;
            val = fmaxf(val, -1e30f);
            alpha = val * m_t + alpha * (1.f - m_t);
            M     = (m_t > 0.5f) ? Mn : M;
        }

        float valid = (tt > 0) ? 1.f : 0.f;
        gold_part += em_g * gmc + tr_g * (gmp * gmc) * valid;
    }

    float M2 = alpha;
    #pragma unroll
    for (int o = 32; o > 0; o >>= 1) M2 = fmaxf(M2, __shfl_xor(M2, o));
    float e2 = __expf(alpha - M2);
    #pragma unroll
    for (int o = 32; o > 0; o >>= 1) e2 += __shfl_xor(e2, o);
    float logZ = M2 + __logf(e2);

    #pragma unroll
    for (int o = 32; o > 0; o >>= 1) gold_part += __shfl_xor(gold_part, o);

    if (lane == 0) ws[b] = logZ - gold_part;
}

// Deterministic final mean over B=128 per-batch results.
__global__ __launch_bounds__(128)
void crf_reduce(const float* __restrict__ ws, float* __restrict__ out)
{
    const int tid = threadIdx.x;
    float v = ws[tid];
    #pragma unroll
    for (int o = 32; o > 0; o >>= 1) v += __shfl_xor(v, o);

    __shared__ float partial[2];
    if ((tid & 63) == 0) partial[tid >> 6] = v;
    __syncthreads();
    if (tid == 0) out[0] = (partial[0] + partial[1]) * (1.0f / (float)B);
}

extern "C" void kernel_launch(void* const* d_in, const int* in_sizes, int n_in,
                              void* d_out, int out_size, void* d_ws, size_t ws_size,
                              hipStream_t stream)
{
    const float* features    = (const float*)d_in[0]; // (B,S,T) f32
    const int*   labels      = (const int*)  d_in[1]; // (B,S) int
    const float* mask        = (const float*)d_in[2]; // (B,S) f32
    const float* transitions = (const float*)d_in[3]; // (T,T) f32
    float* out = (float*)d_out;

    auto need = [](int GG) {
        return (size_t)B * GG * 64 * 64 * sizeof(unsigned short)
             + (size_t)B * GG * sizeof(int) + (size_t)B * sizeof(float);
    };

    if (ws_size >= need(32)) {
        constexpr int GG = 32;
        size_t zbytes = (size_t)B * GG * 64 * 64 * sizeof(unsigned short);
        size_t kbytes = (size_t)B * GG * sizeof(int);
        unsigned short* Zmat = (unsigned short*)d_ws;
        int*   Ks  = (int*)((char*)d_ws + zbytes);
        float* res = (float*)((char*)d_ws + zbytes + kbytes);
        crf_chunk4<GG><<<dim3(B * GG / 4), dim3(256), 0, stream>>>(features, mask, transitions, Zmat, Ks);
        crf_apply<GG><<<dim3(B), dim3(64), 0, stream>>>(features, labels, mask, transitions, Zmat, Ks, res);
        crf_reduce<<<dim3(1), dim3(128), 0, stream>>>(res, out);
    } else if (ws_size >= need(16)) {
        constexpr int GG = 16;
        size_t zbytes = (size_t)B * GG * 64 * 64 * sizeof(unsigned short);
        size_t kbytes = (size_t)B * GG * sizeof(int);
        unsigned short* Zmat = (unsigned short*)d_ws;
        int*   Ks  = (int*)((char*)d_ws + zbytes);
        float* res = (float*)((char*)d_ws + zbytes + kbytes);
        crf_chunk4<GG><<<dim3(B * GG / 4), dim3(256), 0, stream>>>(features, mask, transitions, Zmat, Ks);
        crf_apply<GG><<<dim3(B), dim3(64), 0, stream>>>(features, labels, mask, transitions, Zmat, Ks, res);
        crf_reduce<<<dim3(1), dim3(128), 0, stream>>>(res, out);
    } else {
        float* res = (float*)d_ws;
        crf_fwd_seq<<<dim3(B), dim3(64), 0, stream>>>(features, labels, mask, transitions, res);
        crf_reduce<<<dim3(1), dim3(128), 0, stream>>>(res, out);
    }
}

// Round 12
// 78.156 us; speedup vs baseline: 1.3184x; 1.3184x over previous
//
#include <hip/hip_runtime.h>

#define B 128
#define S 512
#define T 64
#define G 16

typedef float f32x4 __attribute__((ext_vector_type(4)));
typedef _Float16 h2 __attribute__((ext_vector_type(2)));
typedef _Float16 h8 __attribute__((ext_vector_type(8)));

__device__ __forceinline__ float rdlane(float v, int l) {
    return __int_as_float(__builtin_amdgcn_readlane(__float_as_int(v), l));
}
__device__ __forceinline__ unsigned cvtpk_bf16(float lo, float hi) {
    unsigned r;
    asm("v_cvt_pk_bf16_f32 %0, %1, %2" : "=v"(r) : "v"(lo), "v"(hi));
    return r;
}
// packed f32->f16 (RTZ), two f16 in one dword
__device__ __forceinline__ unsigned cvt_pkrtz_u(float lo, float hi) {
    unsigned r;
    asm("v_cvt_pkrtz_f16_f32 %0, %1, %2" : "=v"(r) : "v"(lo), "v"(hi));
    return r;
}
__device__ __forceinline__ float fast_exp2(float x) {
    float r;
    asm("v_exp_f32 %0, %1" : "=v"(r) : "v"(x));
    return r;
}
// A/B fragment k-index for mfma_f32_16x16x32_{bf16,f16}, SPLIT-HALF mapping
// (validated round 6, absmax=0): e=0..3 -> k=4*gq+e ; e=4..7 -> k=16+4*gq+(e-4)
__device__ __forceinline__ int krow(int kt, int gq, int e) {
    return 32 * kt + ((e >> 2) << 4) + 4 * gq + (e & 3);
}

// ============================================================================
// Phase 1, ROUND 12: one wave per (batch, chunk-PAIR). Each wave builds TWO
// independent Z_g products (g0=2q, g1=2q+1) interleaved — chain B's issue
// work fills chain A's stall cycles (MFMA latency, shfl-reduce, mem latency).
// 1024 one-wave workgroups (4/CU) all co-resident -> wall = 1-wave latency.
// Emission/mask prefetch depth 2. launch_bounds(64,2) -> 256-VGPR budget,
// working set ~230 regs, no spill, no AGPR round trips.
// Per chain: diagonal folded into A (rows per-fragment-uniform), C held one
// column of tiles (16 regs), lane-local C->B repack, lag-1 pow2 rescale.
// ============================================================================
template<int GG>
__global__ __launch_bounds__(64, 2)
void crf_chunk2(const float* __restrict__ features,
                const float* __restrict__ mask,
                const float* __restrict__ transitions,
                unsigned short* __restrict__ Zout,
                int* __restrict__ Kout)
{
    constexpr int CLT = S / GG;            // 32 steps per chunk
    __shared__ unsigned short relay[T * 68];   // used once per chain at end

    const int lane = threadIdx.x;
    const int idx  = blockIdx.x;           // (b, pair)
    const int b  = idx / (GG / 2);
    const int q  = idx % (GG / 2);
    const int g0 = 2 * q, g1 = 2 * q + 1;
    const int c  = lane & 15;
    const int gq = lane >> 4;

    // ---- static E^T fragments (f16), shared by both chains ----
    h8 Ef[4][2];
    float emaxv = 1e-10f;
    #pragma unroll
    for (int rt = 0; rt < 4; ++rt)
      #pragma unroll
      for (int kt = 0; kt < 2; ++kt)
        #pragma unroll
        for (int e = 0; e < 8; ++e) {
            int k = krow(kt, gq, e);
            float x = __expf(transitions[k * T + (c + 16*rt)]);
            emaxv = fmaxf(emaxv, x);
            Ef[rt][kt][e] = (_Float16)x;
        }
    #pragma unroll
    for (int o = 32; o > 0; o >>= 1)
        emaxv = fmaxf(emaxv, __shfl_xor(emaxv, o));
    const float dmax = 60000.0f / emaxv;   // keeps A' inside f16 range

    // ---- both chains: Z init = identity (B-fragment layout) ----
    h8 BfA[2][4], BfB[2][4];
    #pragma unroll
    for (int kt = 0; kt < 2; ++kt)
      #pragma unroll
      for (int ct = 0; ct < 4; ++ct)
        #pragma unroll
        for (int e = 0; e < 8; ++e) {
            _Float16 idv = (krow(kt, gq, e) == 16*ct + c) ? (_Float16)1.0f
                                                          : (_Float16)0.0f;
            BfA[kt][ct][e] = idv;
            BfB[kt][ct][e] = idv;
        }

    const float* fb   = features + (size_t)b * S * T;
    const float* colp = fb + c;
    const float* mb   = mask + (size_t)b * S;
    const int t0A = g0 * CLT + 1;
    const int t0B = g1 * CLT + 1;
    const int t1B = (g1 == GG - 1) ? S : (t0B + CLT);  // B may be 1 short

    int kcurA = 0, ktotA = 0, kcurB = 0, ktotB = 0;

    // prefetch pipelines, depth 2 (em rows 16*rt + 4*gq.. as per-lane scalars
    // at col c of rows; actually em[t, c+16*rt])
    float emA1[4], emA2[4], emB1[4], emB2[4];
    #pragma unroll
    for (int rt = 0; rt < 4; ++rt) {
        emA1[rt] = colp[(t0A    ) * T + 16*rt];
        emA2[rt] = colp[(t0A + 1) * T + 16*rt];
        emB1[rt] = colp[(t0B    ) * T + 16*rt];
        emB2[rt] = colp[(t0B + 1) * T + 16*rt];
    }
    float mA1 = mb[t0A], mA2 = mb[t0A + 1];
    float mB1 = mb[t0B], mB2 = mb[min(t0B + 1, S - 1)];

    for (int i = 0; i < CLT; ++i) {
        const int tA = t0A + i;
        const int tB = t0B + i;
        const bool actB = (tB < t1B);

        // consume current, rotate, prefetch t+2 (clamped)
        float emcA[4], emcB[4];
        #pragma unroll
        for (int rt = 0; rt < 4; ++rt) { emcA[rt] = emA1[rt]; emcB[rt] = emB1[rt]; }
        float mcA = mA1, mcB = mB1;
        {
            int tA2 = min(tA + 2, S - 1), tB2 = min(tB + 2, S - 1);
            #pragma unroll
            for (int rt = 0; rt < 4; ++rt) {
                emA1[rt] = emA2[rt];  emA2[rt] = colp[tA2 * T + 16*rt];
                emB1[rt] = emB2[rt];  emB2[rt] = colp[tB2 * T + 16*rt];
            }
            mA1 = mA2; mA2 = mb[tA2];
            mB1 = mB2; mB2 = mb[tB2];
        }

        // ---------- chain A ----------
        if (mcA != 0.0f) {
            const float kcf = (float)kcurA;
            h8 Ap[4][2];
            #pragma unroll
            for (int rt = 0; rt < 4; ++rt) {
                float d = fast_exp2(fmaf(emcA[rt], 1.44269504f, -kcf));
                d = fminf(d, dmax);
                unsigned w = cvt_pkrtz_u(d, d);
                uint4 qs; qs.x = w; qs.y = w; qs.z = w; qs.w = w;
                h8 ds = __builtin_bit_cast(h8, qs);
                Ap[rt][0] = Ef[rt][0] * ds;
                Ap[rt][1] = Ef[rt][1] * ds;
            }
            float mx = 1e-30f;
            #pragma unroll
            for (int ct = 0; ct < 4; ++ct) {
                f32x4 Ct[4];
                #pragma unroll
                for (int tr = 0; tr < 4; ++tr) {
                    f32x4 z = {0.f, 0.f, 0.f, 0.f};
                    z = __builtin_amdgcn_mfma_f32_16x16x32_f16(Ap[tr][0], BfA[0][ct], z, 0, 0, 0);
                    z = __builtin_amdgcn_mfma_f32_16x16x32_f16(Ap[tr][1], BfA[1][ct], z, 0, 0, 0);
                    Ct[tr] = z;
                }
                #pragma unroll
                for (int tr = 0; tr < 4; ++tr)
                    mx = fmaxf(mx, fmaxf(fmaxf(Ct[tr][0], Ct[tr][1]),
                                         fmaxf(Ct[tr][2], Ct[tr][3])));
                uint4 q0v, q1v;
                q0v.x = cvt_pkrtz_u(Ct[0][0], Ct[0][1]);
                q0v.y = cvt_pkrtz_u(Ct[0][2], Ct[0][3]);
                q0v.z = cvt_pkrtz_u(Ct[1][0], Ct[1][1]);
                q0v.w = cvt_pkrtz_u(Ct[1][2], Ct[1][3]);
                q1v.x = cvt_pkrtz_u(Ct[2][0], Ct[2][1]);
                q1v.y = cvt_pkrtz_u(Ct[2][2], Ct[2][3]);
                q1v.z = cvt_pkrtz_u(Ct[3][0], Ct[3][1]);
                q1v.w = cvt_pkrtz_u(Ct[3][2], Ct[3][3]);
                BfA[0][ct] = __builtin_bit_cast(h8, q0v);
                BfA[1][ct] = __builtin_bit_cast(h8, q1v);
            }
            #pragma unroll
            for (int o = 32; o > 0; o >>= 1)
                mx = fmaxf(mx, __shfl_xor(mx, o));
            ktotA += kcurA;
            kcurA = (((__float_as_int(mx) >> 23) & 0xFF) - 127) + 8;
            kcurA = kcurA < -60 ? -60 : (kcurA > 60 ? 60 : kcurA);
        }

        // ---------- chain B ----------
        if (actB && mcB != 0.0f) {
            const float kcf = (float)kcurB;
            h8 Ap[4][2];
            #pragma unroll
            for (int rt = 0; rt < 4; ++rt) {
                float d = fast_exp2(fmaf(emcB[rt], 1.44269504f, -kcf));
                d = fminf(d, dmax);
                unsigned w = cvt_pkrtz_u(d, d);
                uint4 qs; qs.x = w; qs.y = w; qs.z = w; qs.w = w;
                h8 ds = __builtin_bit_cast(h8, qs);
                Ap[rt][0] = Ef[rt][0] * ds;
                Ap[rt][1] = Ef[rt][1] * ds;
            }
            float mx = 1e-30f;
            #pragma unroll
            for (int ct = 0; ct < 4; ++ct) {
                f32x4 Ct[4];
                #pragma unroll
                for (int tr = 0; tr < 4; ++tr) {
                    f32x4 z = {0.f, 0.f, 0.f, 0.f};
                    z = __builtin_amdgcn_mfma_f32_16x16x32_f16(Ap[tr][0], BfB[0][ct], z, 0, 0, 0);
                    z = __builtin_amdgcn_mfma_f32_16x16x32_f16(Ap[tr][1], BfB[1][ct], z, 0, 0, 0);
                    Ct[tr] = z;
                }
                #pragma unroll
                for (int tr = 0; tr < 4; ++tr)
                    mx = fmaxf(mx, fmaxf(fmaxf(Ct[tr][0], Ct[tr][1]),
                                         fmaxf(Ct[tr][2], Ct[tr][3])));
                uint4 q0v, q1v;
                q0v.x = cvt_pkrtz_u(Ct[0][0], Ct[0][1]);
                q0v.y = cvt_pkrtz_u(Ct[0][2], Ct[0][3]);
                q0v.z = cvt_pkrtz_u(Ct[1][0], Ct[1][1]);
                q0v.w = cvt_pkrtz_u(Ct[1][2], Ct[1][3]);
                q1v.x = cvt_pkrtz_u(Ct[2][0], Ct[2][1]);
                q1v.y = cvt_pkrtz_u(Ct[2][2], Ct[2][3]);
                q1v.z = cvt_pkrtz_u(Ct[3][0], Ct[3][1]);
                q1v.w = cvt_pkrtz_u(Ct[3][2], Ct[3][3]);
                BfB[0][ct] = __builtin_bit_cast(h8, q0v);
                BfB[1][ct] = __builtin_bit_cast(h8, q1v);
            }
            #pragma unroll
            for (int o = 32; o > 0; o >>= 1)
                mx = fmaxf(mx, __shfl_xor(mx, o));
            ktotB += kcurB;
            kcurB = (((__float_as_int(mx) >> 23) & 0xFF) - 127) + 8;
            kcurB = kcurB < -60 ? -60 : (kcurB > 60 ? 60 : kcurB);
        }
    }

    // ---- store both Z's (sequential reuse of the relay slab) ----
    #pragma unroll
    for (int chain = 0; chain < 2; ++chain) {
        h8 (*Bf)[4] = chain ? BfB : BfA;
        const int g = chain ? g1 : g0;
        #pragma unroll
        for (int kt = 0; kt < 2; ++kt)
          #pragma unroll
          for (int ct = 0; ct < 4; ++ct) {
              int col = 16*ct + c;
              unsigned dw[4];
              #pragma unroll
              for (int p = 0; p < 4; ++p)
                  dw[p] = cvtpk_bf16((float)Bf[kt][ct][2*p], (float)Bf[kt][ct][2*p+1]);
              uint2 wa; wa.x = dw[0]; wa.y = dw[1];
              uint2 wb; wb.x = dw[2]; wb.y = dw[3];
              *(uint2*)&relay[col * 68 + 32*kt      + 4*gq] = wa;
              *(uint2*)&relay[col * 68 + 32*kt + 16 + 4*gq] = wb;
          }
        asm volatile("s_waitcnt lgkmcnt(0)" ::: "memory");

        unsigned short* zo = Zout + ((size_t)(b * GG + g)) * 64 * 64;
        #pragma unroll
        for (int q8 = 0; q8 < 8; ++q8) {
            unsigned dw[4];
            #pragma unroll
            for (int d = 0; d < 4; ++d) {
                unsigned lo = relay[(8*q8 + 2*d    ) * 68 + lane];
                unsigned hi = relay[(8*q8 + 2*d + 1) * 68 + lane];
                dw[d] = lo | (hi << 16);
            }
            uint4 w; w.x = dw[0]; w.y = dw[1]; w.z = dw[2]; w.w = dw[3];
            *(uint4*)(zo + (size_t)lane * 64 + 8*q8) = w;
        }
        asm volatile("s_waitcnt lgkmcnt(0)" ::: "memory");
        if (lane == 0) Kout[b * GG + g] = chain ? ktotB : ktotA;
    }
}

// ============================================================================
// Phase 2: one wave per batch. v = exp(alpha - max), apply the GG chunk
// matrices sequentially (v <- Z_g v), renormalize by wave-max; plus gold.
// ============================================================================
template<int GG>
__global__ __launch_bounds__(64, 1)
void crf_apply(const float* __restrict__ features,
               const int*   __restrict__ labels,
               const float* __restrict__ mask,
               const float* __restrict__ transitions,
               const unsigned short* __restrict__ Zmat,
               const int*   __restrict__ Kscale,
               float*       __restrict__ res)
{
    __shared__ float trans_lds[T * T];
    __shared__ float bcast[2][T];
    const int lane = threadIdx.x;
    const int b = blockIdx.x;

    for (int i = 0; i < T; ++i)
        trans_lds[i * T + lane] = transitions[i * T + lane];
    __syncthreads();

    const float* fb = features + (size_t)b * S * T;
    const int*   lb = labels + (size_t)b * S;
    const float* mb = mask + (size_t)b * S;

    // ---- gold score (lane i handles t = 64*ch + i) ----
    float gold = 0.f;
    #pragma unroll
    for (int ch = 0; ch < S / T; ++ch) {
        int tt = ch * T + lane;
        int tm1 = tt > 0 ? tt - 1 : 0;
        int la = lb[tt], lp = lb[tm1];
        float mt = mb[tt], mp = mb[tm1];
        float em_g = fb[(size_t)tt * T + la];
        float tr_g = trans_lds[lp * T + la];
        gold += em_g * mt + ((tt > 0) ? tr_g * (mp * mt) : 0.f);
    }

    // ---- v init from alpha_0 = em_0, normalized by wave max ----
    float a0 = fb[lane];
    float A0 = a0;
    #pragma unroll
    for (int o = 32; o > 0; o >>= 1) A0 = fmaxf(A0, __shfl_xor(A0, o));
    float v = __expf(a0 - A0);
    float off = A0;

    // double-buffered Z-row loads (lane j holds row j)
    const unsigned short* zb = Zmat + ((size_t)b * GG) * 64 * 64 + (size_t)lane * 64;
    uint4 cur[8], nxt[8];
    #pragma unroll
    for (int i = 0; i < 8; ++i) cur[i] = ((const uint4*)zb)[i];

    for (int g = 0; g < GG; ++g) {
        if (g + 1 < GG) {
            const uint4* zn = (const uint4*)(zb + (size_t)(g + 1) * 64 * 64);
            #pragma unroll
            for (int i = 0; i < 8; ++i) nxt[i] = zn[i];
        }
        const int buf = g & 1;
        bcast[buf][lane] = v;
        asm volatile("s_waitcnt lgkmcnt(0)" ::: "memory");
        f32x4 vb[16];
        #pragma unroll
        for (int q = 0; q < 16; ++q) vb[q] = ((const f32x4*)bcast[buf])[q];

        float ac0 = 0.f, ac1 = 0.f, ac2 = 0.f, ac3 = 0.f;
        #pragma unroll
        for (int i = 0; i < 8; ++i) {
            unsigned zz[4] = {cur[i].x, cur[i].y, cur[i].z, cur[i].w};
            #pragma unroll
            for (int d = 0; d < 4; ++d) {
                int k = i * 8 + d * 2;
                float f0 = __int_as_float(zz[d] << 16);
                float f1 = __int_as_float(zz[d] & 0xFFFF0000u);
                if ((d & 1) == 0) { ac0 = fmaf(f0, vb[k >> 2][k & 3], ac0);
                                    ac1 = fmaf(f1, vb[(k+1) >> 2][(k+1) & 3], ac1); }
                else             { ac2 = fmaf(f0, vb[k >> 2][k & 3], ac2);
                                    ac3 = fmaf(f1, vb[(k+1) >> 2][(k+1) & 3], ac3); }
            }
        }
        float acc = (ac0 + ac1) + (ac2 + ac3);
        acc = fminf(fmaxf(acc, 0.f), 1e30f);
        float r = acc;
        #pragma unroll
        for (int o = 32; o > 0; o >>= 1) r = fmaxf(r, __shfl_xor(r, o));
        r = fmaxf(r, 1e-30f);
        v = acc / r;
        off += __logf(r) + (float)Kscale[b * GG + g] * 0.69314718056f;
        #pragma unroll
        for (int i = 0; i < 8; ++i) cur[i] = nxt[i];
    }

    float sum = v;
    #pragma unroll
    for (int o = 32; o > 0; o >>= 1) sum += __shfl_xor(sum, o);
    float logZ = __logf(fmaxf(sum, 1e-30f)) + off;

    #pragma unroll
    for (int o = 32; o > 0; o >>= 1) gold += __shfl_xor(gold, o);

    if (lane == 0) res[b] = logZ - gold;
}

// ============================================================================
// Fallback: validated round-3 sequential kernel (used if ws too small)
// ============================================================================
__global__ __launch_bounds__(64, 1)
void crf_fwd_seq(const float* __restrict__ features,
                 const int*   __restrict__ labels,
                 const float* __restrict__ mask,
                 const float* __restrict__ transitions,
                 float*       __restrict__ ws)
{
    __shared__ float trans_lds[T * T];
    __shared__ __align__(16) _Float16 ea_lds[2][T];

    const int lane = threadIdx.x;
    const int b    = blockIdx.x;

    for (int i = 0; i < T; ++i)
        trans_lds[i * T + lane] = transitions[i * T + lane];
    __syncthreads();

    h2 etr[T / 2];
    #pragma unroll
    for (int k = 0; k < T / 2; ++k) {
        etr[k].x = (_Float16)__expf(trans_lds[(2 * k + 0) * T + lane]);
        etr[k].y = (_Float16)__expf(trans_lds[(2 * k + 1) * T + lane]);
    }

    const float* fb = features + (size_t)b * S * T;
    const float* mb = mask + (size_t)b * S;
    const int*   lb = labels + (size_t)b * S;

    float alpha = fb[lane];
    float gold_part = 0.f;
    float M = 0.f;

    float em_n1 = fb[1 * T + lane];
    float em_n2 = fb[2 * T + lane];
    float em_n3 = fb[3 * T + lane];

    int   lab_c = lb[lane];
    int   lab_p = lb[lane > 0 ? lane - 1 : 0];
    float m_c   = mb[lane];
    float m_p   = mb[lane > 0 ? lane - 1 : 0];

    for (int ch = 0; ch < S / T; ++ch) {
        const int base = ch * T;
        const int tt   = base + lane;

        const int   glab  = lab_c;
        const int   glabp = lab_p;
        const float gmc   = m_c;
        const float gmp   = m_p;
        const float mreg  = m_c;

        float em_g = fb[(size_t)tt * T + glab];
        float tr_g = trans_lds[glabp * T + glab];

        {
            int tn  = tt + T;  if (tn > S - 1) tn = S - 1;
            int tnp = tn - 1;  if (tnp < 0) tnp = 0;
            lab_c = lb[tn]; lab_p = lb[tnp];
            m_c   = mb[tn]; m_p   = mb[tnp];
        }

        const int i0 = (ch == 0) ? 1 : 0;
        #pragma unroll 4
        for (int i = i0; i < T; ++i) {
            const int t = base + i;
            float em = em_n1;
            em_n1 = em_n2; em_n2 = em_n3;
            int tn = t + 3; if (tn > S - 1) tn = S - 1;
            em_n3 = fb[tn * T + lane];

            float ea = __expf(alpha - M);
            ea_lds[t & 1][lane] = (_Float16)ea;
            asm volatile("s_waitcnt lgkmcnt(0)" ::: "memory");

            const uint4* ep = (const uint4*)&ea_lds[t & 1][0];
            float a0 = 0.f, a1 = 0.f, a2 = 0.f, a3 = 0.f;
            #pragma unroll
            for (int q = 0; q < 8; ++q) {
                uint4 r = ep[q];
                a0 = __builtin_amdgcn_fdot2(__builtin_bit_cast(h2, r.x), etr[4 * q + 0], a0, false);
                a1 = __builtin_amdgcn_fdot2(__builtin_bit_cast(h2, r.y), etr[4 * q + 1], a1, false);
                a2 = __builtin_amdgcn_fdot2(__builtin_bit_cast(h2, r.z), etr[4 * q + 2], a2, false);
                a3 = __builtin_amdgcn_fdot2(__builtin_bit_cast(h2, r.w), etr[4 * q + 3], a3, false);
            }
            float s = (a0 + a1) + (a2 + a3);

            float m_t = rdlane(mreg, i);
            float s1  = rdlane(s, 1);
            float em1 = rdlane(em, 1);
            float Mn  = M + __logf(s1) + em1;

            float val = M + __logf(s) + em;
            val = fmaxf(val, -1e30f);
            alpha = val * m_t + alpha * (1.f - m_t);
            M     = (m_t > 0.5f) ? Mn : M;
        }

        float valid = (tt > 0) ? 1.f : 0.f;
        gold_part += em_g * gmc + tr_g * (gmp * gmc) * valid;
    }

    float M2 = alpha;
    #pragma unroll
    for (int o = 32; o > 0; o >>= 1) M2 = fmaxf(M2, __shfl_xor(M2, o));
    float e2 = __expf(alpha - M2);
    #pragma unroll
    for (int o = 32; o > 0; o >>= 1) e2 += __shfl_xor(e2, o);
    float logZ = M2 + __logf(e2);

    #pragma unroll
    for (int o = 32; o > 0; o >>= 1) gold_part += __shfl_xor(gold_part, o);

    if (lane == 0) ws[b] = logZ - gold_part;
}

// Deterministic final mean over B=128 per-batch results.
__global__ __launch_bounds__(128)
void crf_reduce(const float* __restrict__ ws, float* __restrict__ out)
{
    const int tid = threadIdx.x;
    float v = ws[tid];
    #pragma unroll
    for (int o = 32; o > 0; o >>= 1) v += __shfl_xor(v, o);

    __shared__ float partial[2];
    if ((tid & 63) == 0) partial[tid >> 6] = v;
    __syncthreads();
    if (tid == 0) out[0] = (partial[0] + partial[1]) * (1.0f / (float)B);
}

extern "C" void kernel_launch(void* const* d_in, const int* in_sizes, int n_in,
                              void* d_out, int out_size, void* d_ws, size_t ws_size,
                              hipStream_t stream)
{
    const float* features    = (const float*)d_in[0]; // (B,S,T) f32
    const int*   labels      = (const int*)  d_in[1]; // (B,S) int
    const float* mask        = (const float*)d_in[2]; // (B,S) f32
    const float* transitions = (const float*)d_in[3]; // (T,T) f32
    float* out = (float*)d_out;

    const size_t zbytes = (size_t)B * G * 64 * 64 * sizeof(unsigned short); // 16 MB
    const size_t kbytes = (size_t)B * G * sizeof(int);
    const size_t need   = zbytes + kbytes + (size_t)B * sizeof(float);

    if (ws_size >= need) {
        unsigned short* Zmat = (unsigned short*)d_ws;
        int*   Ks  = (int*)((char*)d_ws + zbytes);
        float* res = (float*)((char*)d_ws + zbytes + kbytes);
        crf_chunk2<G><<<dim3(B * G / 2), dim3(64), 0, stream>>>(features, mask, transitions, Zmat, Ks);
        crf_apply<G><<<dim3(B), dim3(64), 0, stream>>>(features, labels, mask, transitions, Zmat, Ks, res);
        crf_reduce<<<dim3(1), dim3(128), 0, stream>>>(res, out);
    } else {
        float* res = (float*)d_ws;
        crf_fwd_seq<<<dim3(B), dim3(64), 0, stream>>>(features, labels, mask, transitions, res);
        crf_reduce<<<dim3(1), dim3(128), 0, stream>>>(res, out);
    }
}

// Round 13
// 62.161 us; speedup vs baseline: 1.6576x; 1.2573x over previous
//
#include <hip/hip_runtime.h>

#define B 128
#define S 512
#define T 64
#define G 16

typedef short bf16x8 __attribute__((ext_vector_type(8)));
typedef float f32x4 __attribute__((ext_vector_type(4)));
typedef float f32x2 __attribute__((ext_vector_type(2)));
typedef _Float16 h2 __attribute__((ext_vector_type(2)));

__device__ __forceinline__ float rdlane(float v, int l) {
    return __int_as_float(__builtin_amdgcn_readlane(__float_as_int(v), l));
}
__device__ __forceinline__ unsigned cvtpk_bf16(float lo, float hi) {
    unsigned r;
    asm("v_cvt_pk_bf16_f32 %0, %1, %2" : "=v"(r) : "v"(lo), "v"(hi));
    return r;
}
__device__ __forceinline__ float fast_exp2(float x) {
    float r;
    asm("v_exp_f32 %0, %1" : "=v"(r) : "v"(x));
    return r;
}
// A/B fragment k-index for mfma_f32_16x16x32_bf16, SPLIT-HALF mapping
// (validated round 6, absmax=0): e=0..3 -> k=4*gq+e ; e=4..7 -> k=16+4*gq+(e-4)
__device__ __forceinline__ int krow(int kt, int gq, int e) {
    return 32 * kt + ((e >> 2) << 4) + 4 * gq + (e & 3);
}

// ============================================================================
// Phase 1, ROUND 13: one wave per (batch, chunk); Z product in **bf16**
// (f32-range exponent) -> the pow2 rescale is LAZY: local max tracked per
// step (cheap fmax tree), cross-lane reduce only every 4th step (lag-2 to
// its application) -> reduce is OFF the critical path. Per-step chain is
// MFMA -> cvt_pk_bf16 -> MFMA. E^T held in f32 (f32x2 -> v_pk_mul_f32),
// d folded per-row, converted straight to bf16. launch_bounds(64,2) gives
// a 256-VGPR budget: whole live set in arch VGPRs (no AGPR copies).
// Safety: worst-case growth 2^19/step; <=6 steps between rescales from a
// 2^0-normalized state stays far below bf16/f32 max 2^127.
// ============================================================================
template<int GG>
__global__ __launch_bounds__(64, 2)
void crf_chunk_bf(const float* __restrict__ features,
                  const float* __restrict__ mask,
                  const float* __restrict__ transitions,
                  unsigned short* __restrict__ Zout,
                  int* __restrict__ Kout)
{
    constexpr int CLT = S / GG;                // 32
    __shared__ unsigned short relay[T * 68];   // used ONCE at end

    const int lane = threadIdx.x;
    const int b  = blockIdx.x / GG;
    const int g  = blockIdx.x % GG;
    const int c  = lane & 15;
    const int gq = lane >> 4;

    // ---- static E^T in f32, pre-paired for cvt_pk: e32[rt][kt][w] =
    //      { exp(W[k0][i]), exp(W[k0+1][i]) }, k0 = krow(kt,gq,2w), i=c+16rt
    f32x2 e32[4][2][4];                        // 64 VGPRs
    #pragma unroll
    for (int rt = 0; rt < 4; ++rt)
      #pragma unroll
      for (int kt = 0; kt < 2; ++kt)
        #pragma unroll
        for (int w = 0; w < 4; ++w) {
            int k0 = krow(kt, gq, 2 * w);
            e32[rt][kt][w][0] = __expf(transitions[k0       * T + (c + 16*rt)]);
            e32[rt][kt][w][1] = __expf(transitions[(k0 + 1) * T + (c + 16*rt)]);
        }

    // ---- Z init = identity, in B-fragment layout (bf16 1.0 = 0x3F80) ----
    bf16x8 Bf[2][4];
    #pragma unroll
    for (int kt = 0; kt < 2; ++kt)
      #pragma unroll
      for (int ct = 0; ct < 4; ++ct)
        #pragma unroll
        for (int e = 0; e < 8; ++e)
            Bf[kt][ct][e] = (krow(kt, gq, e) == 16*ct + c) ? (short)0x3F80
                                                           : (short)0;

    const float* fb   = features + (size_t)b * S * T;
    const float* colp = fb + c;
    const float* mb   = mask + (size_t)b * S;
    const int t0 = g * CLT + 1;
    const int t1 = (g == GG - 1) ? S : (t0 + CLT);

    const f32x4 zero4 = {0.f, 0.f, 0.f, 0.f};  // shared C-in for first MFMA

    int ktot = 0;
    float zloc = 1.0f;     // running local max since last measure
    float mxr  = 1.0f;     // reduced max from last measure (lag-2)

    // emission/mask prefetch, depth 2
    float em1[4], em2[4];
    #pragma unroll
    for (int rt = 0; rt < 4; ++rt) {
        em1[rt] = colp[t0 * T + 16*rt];
        em2[rt] = colp[min(t0 + 1, S - 1) * T + 16*rt];
    }
    float m1 = mb[t0], m2 = mb[min(t0 + 1, S - 1)];

    for (int w = 0; w < CLT / 4; ++w) {
        #pragma unroll
        for (int j = 0; j < 4; ++j) {
            const int i = 4 * w + j;
            const int t = t0 + i;
            const bool act = (t < t1);

            float emc[4];
            #pragma unroll
            for (int rt = 0; rt < 4; ++rt) emc[rt] = em1[rt];
            float mc = m1;
            {   // rotate + prefetch t+2
                int t2 = min(t + 2, S - 1);
                #pragma unroll
                for (int rt = 0; rt < 4; ++rt) {
                    em1[rt] = em2[rt];
                    em2[rt] = colp[t2 * T + 16*rt];
                }
                m1 = m2; m2 = mb[t2];
            }

            int kc = 0;
            if (j == 0) {   // finish measure from window w-1
                kc = ((__float_as_int(mxr) >> 23) & 0xFF) - 127;
                kc = kc < -30 ? -30 : (kc > 60 ? 60 : kc);
            }

            if (act && mc != 0.0f) {
                const float kcf = (j == 0) ? (float)kc : 0.0f;
                // A' = (d .* E^T) in bf16; d = exp2(em*log2e - kc)
                bf16x8 Ap[4][2];
                #pragma unroll
                for (int rt = 0; rt < 4; ++rt) {
                    float d = fast_exp2(fmaf(emc[rt], 1.44269504f, -kcf));
                    f32x2 dd; dd[0] = d; dd[1] = d;
                    #pragma unroll
                    for (int kt = 0; kt < 2; ++kt) {
                        unsigned dw[4];
                        #pragma unroll
                        for (int q = 0; q < 4; ++q) {
                            f32x2 p = e32[rt][kt][q] * dd;   // v_pk_mul_f32
                            dw[q] = cvtpk_bf16(p[0], p[1]);
                        }
                        uint4 qq; qq.x = dw[0]; qq.y = dw[1]; qq.z = dw[2]; qq.w = dw[3];
                        Ap[rt][kt] = __builtin_bit_cast(bf16x8, qq);
                    }
                }
                if (j == 0) ktot += kc;

                // per output-column: 8 MFMAs -> local-max update -> repack
                #pragma unroll
                for (int ct = 0; ct < 4; ++ct) {
                    f32x4 Ct[4];
                    #pragma unroll
                    for (int tr = 0; tr < 4; ++tr) {
                        f32x4 z = __builtin_amdgcn_mfma_f32_16x16x32_bf16(Ap[tr][0], Bf[0][ct], zero4, 0, 0, 0);
                        z = __builtin_amdgcn_mfma_f32_16x16x32_bf16(Ap[tr][1], Bf[1][ct], z, 0, 0, 0);
                        Ct[tr] = z;
                    }
                    #pragma unroll
                    for (int tr = 0; tr < 4; ++tr)
                        zloc = fmaxf(zloc, fmaxf(fmaxf(Ct[tr][0], Ct[tr][1]),
                                                 fmaxf(Ct[tr][2], Ct[tr][3])));
                    uint4 q0, q1;
                    q0.x = cvtpk_bf16(Ct[0][0], Ct[0][1]);
                    q0.y = cvtpk_bf16(Ct[0][2], Ct[0][3]);
                    q0.z = cvtpk_bf16(Ct[1][0], Ct[1][1]);
                    q0.w = cvtpk_bf16(Ct[1][2], Ct[1][3]);
                    q1.x = cvtpk_bf16(Ct[2][0], Ct[2][1]);
                    q1.y = cvtpk_bf16(Ct[2][2], Ct[2][3]);
                    q1.z = cvtpk_bf16(Ct[3][0], Ct[3][1]);
                    q1.w = cvtpk_bf16(Ct[3][2], Ct[3][3]);
                    Bf[0][ct] = __builtin_bit_cast(bf16x8, q0);
                    Bf[1][ct] = __builtin_bit_cast(bf16x8, q1);
                }
            }

            if (j == 2) {   // launch cross-lane reduce (consumed next window)
                float mr = zloc;
                #pragma unroll
                for (int o = 32; o > 0; o >>= 1)
                    mr = fmaxf(mr, __shfl_xor(mr, o));
                mxr  = mr;
                zloc = 1.0f;
            }
        }
    }

    // ---- ONE-TIME relayout to row-major bf16 Zout via LDS ----
    #pragma unroll
    for (int kt = 0; kt < 2; ++kt)
      #pragma unroll
      for (int ct = 0; ct < 4; ++ct) {
          uint4 q = __builtin_bit_cast(uint4, Bf[kt][ct]);
          int col = 16*ct + c;
          uint2 wa; wa.x = q.x; wa.y = q.y;     // rows 32kt+4gq+0..3
          uint2 wb; wb.x = q.z; wb.y = q.w;     // rows 32kt+16+4gq+0..3
          *(uint2*)&relay[col * 68 + 32*kt      + 4*gq] = wa;
          *(uint2*)&relay[col * 68 + 32*kt + 16 + 4*gq] = wb;
      }
    asm volatile("s_waitcnt lgkmcnt(0)" ::: "memory");

    unsigned short* zo = Zout + ((size_t)(b * GG + g)) * 64 * 64;
    #pragma unroll
    for (int q8 = 0; q8 < 8; ++q8) {
        unsigned dw[4];
        #pragma unroll
        for (int d = 0; d < 4; ++d) {
            unsigned lo = relay[(8*q8 + 2*d    ) * 68 + lane];
            unsigned hi = relay[(8*q8 + 2*d + 1) * 68 + lane];
            dw[d] = lo | (hi << 16);
        }
        uint4 wv; wv.x = dw[0]; wv.y = dw[1]; wv.z = dw[2]; wv.w = dw[3];
        *(uint4*)(zo + (size_t)lane * 64 + 8*q8) = wv;
    }
    if (lane == 0) Kout[b * GG + g] = ktot;
}

// ============================================================================
// Phase 2: one wave per batch. v <- Z_g v sequentially; normalizer = exact
// pow2 from lane-1's exponent (readlane + int ops, no wave reduce, no logf).
// esum accumulates integer log2-scale; folded in once at the end.
// ============================================================================
template<int GG>
__global__ __launch_bounds__(64, 1)
void crf_apply(const float* __restrict__ features,
               const int*   __restrict__ labels,
               const float* __restrict__ mask,
               const float* __restrict__ transitions,
               const unsigned short* __restrict__ Zmat,
               const int*   __restrict__ Kscale,
               float*       __restrict__ res)
{
    __shared__ float trans_lds[T * T];
    __shared__ float bcast[2][T];
    const int lane = threadIdx.x;
    const int b = blockIdx.x;

    for (int i = 0; i < T; ++i)
        trans_lds[i * T + lane] = transitions[i * T + lane];
    __syncthreads();

    const float* fb = features + (size_t)b * S * T;
    const int*   lb = labels + (size_t)b * S;
    const float* mb = mask + (size_t)b * S;

    // ---- gold score (lane i handles t = 64*ch + i) ----
    float gold = 0.f;
    #pragma unroll
    for (int ch = 0; ch < S / T; ++ch) {
        int tt = ch * T + lane;
        int tm1 = tt > 0 ? tt - 1 : 0;
        int la = lb[tt], lp = lb[tm1];
        float mt = mb[tt], mp = mb[tm1];
        float em_g = fb[(size_t)tt * T + la];
        float tr_g = trans_lds[lp * T + la];
        gold += em_g * mt + ((tt > 0) ? tr_g * (mp * mt) : 0.f);
    }

    // ---- v init from alpha_0 = em_0, normalized by wave max (one-time) ----
    float a0 = fb[lane];
    float A0 = a0;
    #pragma unroll
    for (int o = 32; o > 0; o >>= 1) A0 = fmaxf(A0, __shfl_xor(A0, o));
    float v = __expf(a0 - A0);

    int esum = 0;

    // double-buffered Z-row loads (lane j holds row j)
    const unsigned short* zb = Zmat + ((size_t)b * GG) * 64 * 64 + (size_t)lane * 64;
    uint4 cur[8], nxt[8];
    #pragma unroll
    for (int i = 0; i < 8; ++i) cur[i] = ((const uint4*)zb)[i];

    for (int g = 0; g < GG; ++g) {
        if (g + 1 < GG) {
            const uint4* zn = (const uint4*)(zb + (size_t)(g + 1) * 64 * 64);
            #pragma unroll
            for (int i = 0; i < 8; ++i) nxt[i] = zn[i];
        }
        const int buf = g & 1;
        bcast[buf][lane] = v;
        asm volatile("s_waitcnt lgkmcnt(0)" ::: "memory");
        f32x4 vb[16];
        #pragma unroll
        for (int q = 0; q < 16; ++q) vb[q] = ((const f32x4*)bcast[buf])[q];

        float ac0 = 0.f, ac1 = 0.f, ac2 = 0.f, ac3 = 0.f;
        #pragma unroll
        for (int i = 0; i < 8; ++i) {
            unsigned zz[4] = {cur[i].x, cur[i].y, cur[i].z, cur[i].w};
            #pragma unroll
            for (int d = 0; d < 4; ++d) {
                int k = i * 8 + d * 2;
                float f0 = __int_as_float(zz[d] << 16);
                float f1 = __int_as_float(zz[d] & 0xFFFF0000u);
                if ((d & 1) == 0) { ac0 = fmaf(f0, vb[k >> 2][k & 3], ac0);
                                    ac1 = fmaf(f1, vb[(k+1) >> 2][(k+1) & 3], ac1); }
                else             { ac2 = fmaf(f0, vb[k >> 2][k & 3], ac2);
                                    ac3 = fmaf(f1, vb[(k+1) >> 2][(k+1) & 3], ac3); }
            }
        }
        float acc = (ac0 + ac1) + (ac2 + ac3);

        // exact pow2 normalizer from lane 1's exponent (lane 0 is PAD -> 0)
        float a1 = fmaxf(rdlane(acc, 1), 1e-30f);
        int e = ((__float_as_int(a1) >> 23) & 0xFF) - 127;
        v = acc * __int_as_float((unsigned)(127 - e) << 23);
        esum += e + Kscale[b * GG + g];

        #pragma unroll
        for (int i = 0; i < 8; ++i) cur[i] = nxt[i];
    }

    float sum = v;
    #pragma unroll
    for (int o = 32; o > 0; o >>= 1) sum += __shfl_xor(sum, o);
    float logZ = __logf(fmaxf(sum, 1e-30f)) + A0 + (float)esum * 0.69314718056f;

    #pragma unroll
    for (int o = 32; o > 0; o >>= 1) gold += __shfl_xor(gold, o);

    if (lane == 0) res[b] = logZ - gold;
}

// ============================================================================
// Fallback: validated round-3 sequential kernel (used if ws too small)
// ============================================================================
__global__ __launch_bounds__(64, 1)
void crf_fwd_seq(const float* __restrict__ features,
                 const int*   __restrict__ labels,
                 const float* __restrict__ mask,
                 const float* __restrict__ transitions,
                 float*       __restrict__ ws)
{
    __shared__ float trans_lds[T * T];
    __shared__ __align__(16) _Float16 ea_lds[2][T];

    const int lane = threadIdx.x;
    const int b    = blockIdx.x;

    for (int i = 0; i < T; ++i)
        trans_lds[i * T + lane] = transitions[i * T + lane];
    __syncthreads();

    h2 etr[T / 2];
    #pragma unroll
    for (int k = 0; k < T / 2; ++k) {
        etr[k].x = (_Float16)__expf(trans_lds[(2 * k + 0) * T + lane]);
        etr[k].y = (_Float16)__expf(trans_lds[(2 * k + 1) * T + lane]);
    }

    const float* fb = features + (size_t)b * S * T;
    const float* mb = mask + (size_t)b * S;
    const int*   lb = labels + (size_t)b * S;

    float alpha = fb[lane];
    float gold_part = 0.f;
    float M = 0.f;

    float em_n1 = fb[1 * T + lane];
    float em_n2 = fb[2 * T + lane];
    float em_n3 = fb[3 * T + lane];

    int   lab_c = lb[lane];
    int   lab_p = lb[lane > 0 ? lane - 1 : 0];
    float m_c   = mb[lane];
    float m_p   = mb[lane > 0 ? lane - 1 : 0];

    for (int ch = 0; ch < S / T; ++ch) {
        const int base = ch * T;
        const int tt   = base + lane;

        const int   glab  = lab_c;
        const int   glabp = lab_p;
        const float gmc   = m_c;
        const float gmp   = m_p;
        const float mreg  = m_c;

        float em_g = fb[(size_t)tt * T + glab];
        float tr_g = trans_lds[glabp * T + glab];

        {
            int tn  = tt + T;  if (tn > S - 1) tn = S - 1;
            int tnp = tn - 1;  if (tnp < 0) tnp = 0;
            lab_c = lb[tn]; lab_p = lb[tnp];
            m_c   = mb[tn]; m_p   = mb[tnp];
        }

        const int i0 = (ch == 0) ? 1 : 0;
        #pragma unroll 4
        for (int i = i0; i < T; ++i) {
            const int t = base + i;
            float em = em_n1;
            em_n1 = em_n2; em_n2 = em_n3;
            int tn = t + 3; if (tn > S - 1) tn = S - 1;
            em_n3 = fb[tn * T + lane];

            float ea = __expf(alpha - M);
            ea_lds[t & 1][lane] = (_Float16)ea;
            asm volatile("s_waitcnt lgkmcnt(0)" ::: "memory");

            const uint4* ep = (const uint4*)&ea_lds[t & 1][0];
            float a0 = 0.f, a1 = 0.f, a2 = 0.f, a3 = 0.f;
            #pragma unroll
            for (int q = 0; q < 8; ++q) {
                uint4 r = ep[q];
                a0 = __builtin_amdgcn_fdot2(__builtin_bit_cast(h2, r.x), etr[4 * q + 0], a0, false);
                a1 = __builtin_amdgcn_fdot2(__builtin_bit_cast(h2, r.y), etr[4 * q + 1], a1, false);
                a2 = __builtin_amdgcn_fdot2(__builtin_bit_cast(h2, r.z), etr[4 * q + 2], a2, false);
                a3 = __builtin_amdgcn_fdot2(__builtin_bit_cast(h2, r.w), etr[4 * q + 3], a3, false);
            }
            float s = (a0 + a1) + (a2 + a3);

            float m_t = rdlane(mreg, i);
            float s1  = rdlane(s, 1);
            float em1 = rdlane(em, 1);
            float Mn  = M + __logf(s1) + em1;

            float val = M + __logf(s) + em;
            val = fmaxf(val, -1e30f);
            alpha = val * m_t + alpha * (1.f - m_t);
            M     = (m_t > 0.5f) ? Mn : M;
        }

        float valid = (tt > 0) ? 1.f : 0.f;
        gold_part += em_g * gmc + tr_g * (gmp * gmc) * valid;
    }

    float M2 = alpha;
    #pragma unroll
    for (int o = 32; o > 0; o >>= 1) M2 = fmaxf(M2, __shfl_xor(M2, o));
    float e2 = __expf(alpha - M2);
    #pragma unroll
    for (int o = 32; o > 0; o >>= 1) e2 += __shfl_xor(e2, o);
    float logZ = M2 + __logf(e2);

    #pragma unroll
    for (int o = 32; o > 0; o >>= 1) gold_part += __shfl_xor(gold_part, o);

    if (lane == 0) ws[b] = logZ - gold_part;
}

// Deterministic final mean over B=128 per-batch results.
__global__ __launch_bounds__(128)
void crf_reduce(const float* __restrict__ ws, float* __restrict__ out)
{
    const int tid = threadIdx.x;
    float v = ws[tid];
    #pragma unroll
    for (int o = 32; o > 0; o >>= 1) v += __shfl_xor(v, o);

    __shared__ float partial[2];
    if ((tid & 63) == 0) partial[tid >> 6] = v;
    __syncthreads();
    if (tid == 0) out[0] = (partial[0] + partial[1]) * (1.0f / (float)B);
}

extern "C" void kernel_launch(void* const* d_in, const int* in_sizes, int n_in,
                              void* d_out, int out_size, void* d_ws, size_t ws_size,
                              hipStream_t stream)
{
    const float* features    = (const float*)d_in[0]; // (B,S,T) f32
    const int*   labels      = (const int*)  d_in[1]; // (B,S) int
    const float* mask        = (const float*)d_in[2]; // (B,S) f32
    const float* transitions = (const float*)d_in[3]; // (T,T) f32
    float* out = (float*)d_out;

    const size_t zbytes = (size_t)B * G * 64 * 64 * sizeof(unsigned short); // 16 MB
    const size_t kbytes = (size_t)B * G * sizeof(int);
    const size_t need   = zbytes + kbytes + (size_t)B * sizeof(float);

    if (ws_size >= need) {
        unsigned short* Zmat = (unsigned short*)d_ws;
        int*   Ks  = (int*)((char*)d_ws + zbytes);
        float* res = (float*)((char*)d_ws + zbytes + kbytes);
        crf_chunk_bf<G><<<dim3(B * G), dim3(64), 0, stream>>>(features, mask, transitions, Zmat, Ks);
        crf_apply<G><<<dim3(B), dim3(64), 0, stream>>>(features, labels, mask, transitions, Zmat, Ks, res);
        crf_reduce<<<dim3(1), dim3(128), 0, stream>>>(res, out);
    } else {
        float* res = (float*)d_ws;
        crf_fwd_seq<<<dim3(B), dim3(64), 0, stream>>>(features, labels, mask, transitions, res);
        crf_reduce<<<dim3(1), dim3(128), 0, stream>>>(res, out);
    }
}